// Round 1
// baseline (145.120 us; speedup 1.0000x reference)
//
#include <hip/hip_runtime.h>

// Row-wise max -> mask (input == row_max) as int32.
// Input: [N=200704, D=512] fp32. Output: [N, 512] int32.
// One wave (64 lanes) per row: 64 lanes x 8 floats = 512 elements.

__global__ __launch_bounds__(256) void rowmax_mask_kernel(
    const float* __restrict__ in, int* __restrict__ out, int nrows) {
    const int wave = threadIdx.x >> 6;   // 0..3 (4 waves per block)
    const int lane = threadIdx.x & 63;
    const int row  = blockIdx.x * 4 + wave;
    if (row >= nrows) return;

    const size_t rowbase = (size_t)row * 512;
    const float4* rin = reinterpret_cast<const float4*>(in + rowbase);

    // Two coalesced 1 KB segments per wave.
    float4 a = rin[lane];        // cols [lane*4, lane*4+4)
    float4 b = rin[lane + 64];   // cols [256 + lane*4, ...)

    float m = fmaxf(fmaxf(fmaxf(a.x, a.y), fmaxf(a.z, a.w)),
                    fmaxf(fmaxf(b.x, b.y), fmaxf(b.z, b.w)));

    // Butterfly max across the 64-lane wave.
    #pragma unroll
    for (int off = 32; off > 0; off >>= 1)
        m = fmaxf(m, __shfl_xor(m, off, 64));

    int4 oa, ob;
    oa.x = (a.x == m); oa.y = (a.y == m); oa.z = (a.z == m); oa.w = (a.w == m);
    ob.x = (b.x == m); ob.y = (b.y == m); ob.z = (b.z == m); ob.w = (b.w == m);

    int4* rout = reinterpret_cast<int4*>(out + rowbase);
    rout[lane]      = oa;
    rout[lane + 64] = ob;
}

extern "C" void kernel_launch(void* const* d_in, const int* in_sizes, int n_in,
                              void* d_out, int out_size, void* d_ws, size_t ws_size,
                              hipStream_t stream) {
    const float* in = (const float*)d_in[0];
    int* out = (int*)d_out;
    const int D = 512;
    const int nrows = in_sizes[0] / D;           // 200704
    const int rows_per_block = 4;                // 4 waves/block
    const int grid = (nrows + rows_per_block - 1) / rows_per_block;
    rowmax_mask_kernel<<<grid, 256, 0, stream>>>(in, out, nrows);
}

// Round 2
// 141.169 us; speedup vs baseline: 1.0280x; 1.0280x over previous
//
#include <hip/hip_runtime.h>

// Row-wise max -> mask (input == row_max) as int32.
// Input: [N=200704, D=512] fp32. Output: [N, 512] int32.
// One wave (64 lanes) per row: 64 lanes x 8 floats = 512 elements.
// Grid-stride persistent waves, 2 rows/iter for MLP, non-temporal streams.

typedef float f32x4 __attribute__((ext_vector_type(4)));
typedef int   i32x4 __attribute__((ext_vector_type(4)));

__global__ __launch_bounds__(256) void rowmax_mask_kernel(
    const float* __restrict__ in, int* __restrict__ out, int nrows) {
    const int lane   = threadIdx.x & 63;
    const int gwave  = (blockIdx.x * 256 + threadIdx.x) >> 6;
    const int nwaves = (gridDim.x * 256) >> 6;

    // nrows is even (200704), row is always even -> row+1 is in-bounds.
    for (int row = gwave * 2; row < nrows; row += nwaves * 2) {
        const f32x4* r0 = reinterpret_cast<const f32x4*>(in + (size_t)row * 512);
        const f32x4* r1 = reinterpret_cast<const f32x4*>(in + (size_t)(row + 1) * 512);

        // 4 independent 16B loads in flight (2 rows).
        f32x4 a0 = __builtin_nontemporal_load(r0 + lane);
        f32x4 b0 = __builtin_nontemporal_load(r0 + lane + 64);
        f32x4 a1 = __builtin_nontemporal_load(r1 + lane);
        f32x4 b1 = __builtin_nontemporal_load(r1 + lane + 64);

        float m0 = fmaxf(fmaxf(fmaxf(a0.x, a0.y), fmaxf(a0.z, a0.w)),
                         fmaxf(fmaxf(b0.x, b0.y), fmaxf(b0.z, b0.w)));
        float m1 = fmaxf(fmaxf(fmaxf(a1.x, a1.y), fmaxf(a1.z, a1.w)),
                         fmaxf(fmaxf(b1.x, b1.y), fmaxf(b1.z, b1.w)));

        // Two interleaved independent butterfly chains across the 64-lane wave.
        #pragma unroll
        for (int off = 32; off > 0; off >>= 1) {
            m0 = fmaxf(m0, __shfl_xor(m0, off, 64));
            m1 = fmaxf(m1, __shfl_xor(m1, off, 64));
        }

        i32x4 oa0, ob0, oa1, ob1;
        oa0.x = (a0.x == m0); oa0.y = (a0.y == m0); oa0.z = (a0.z == m0); oa0.w = (a0.w == m0);
        ob0.x = (b0.x == m0); ob0.y = (b0.y == m0); ob0.z = (b0.z == m0); ob0.w = (b0.w == m0);
        oa1.x = (a1.x == m1); oa1.y = (a1.y == m1); oa1.z = (a1.z == m1); oa1.w = (a1.w == m1);
        ob1.x = (b1.x == m1); ob1.y = (b1.y == m1); ob1.z = (b1.z == m1); ob1.w = (b1.w == m1);

        i32x4* w0 = reinterpret_cast<i32x4*>(out + (size_t)row * 512);
        i32x4* w1 = reinterpret_cast<i32x4*>(out + (size_t)(row + 1) * 512);
        __builtin_nontemporal_store(oa0, w0 + lane);
        __builtin_nontemporal_store(ob0, w0 + lane + 64);
        __builtin_nontemporal_store(oa1, w1 + lane);
        __builtin_nontemporal_store(ob1, w1 + lane + 64);
    }
}

extern "C" void kernel_launch(void* const* d_in, const int* in_sizes, int n_in,
                              void* d_out, int out_size, void* d_ws, size_t ws_size,
                              hipStream_t stream) {
    const float* in = (const float*)d_in[0];
    int* out = (int*)d_out;
    const int D = 512;
    const int nrows = in_sizes[0] / D;   // 200704
    // Persistent grid: ~8 blocks/CU ceiling, grid-stride the rest.
    int grid = 2048;
    const int max_needed = (nrows + 7) / 8;   // 4 waves/block * 2 rows/wave
    if (grid > max_needed) grid = max_needed;
    rowmax_mask_kernel<<<grid, 256, 0, stream>>>(in, out, nrows);
}

// Round 3
// 140.963 us; speedup vs baseline: 1.0295x; 1.0015x over previous
//
#include <hip/hip_runtime.h>

// Row-wise max -> mask (input == row_max) as int32.
// Input: [N=200704, D=512] fp32. Output: [N, 512] int32.
// One wave per row-pair: 64 lanes x 8 floats = 512 elements per row.
// Persistent grid-stride waves, software-pipelined: next iteration's loads
// are issued before the current iteration's reduce+store, so HBM reads stay
// in flight under the shuffle chain.

typedef float f32x4 __attribute__((ext_vector_type(4)));
typedef int   i32x4 __attribute__((ext_vector_type(4)));

__global__ __launch_bounds__(256) void rowmax_mask_kernel(
    const float* __restrict__ in, int* __restrict__ out, int nrows) {
    const int lane   = threadIdx.x & 63;
    const int gwave  = (blockIdx.x * 256 + threadIdx.x) >> 6;
    const int nwaves = (gridDim.x * 256) >> 6;
    const int stride = nwaves * 2;   // rows per grid-stride step

    int row = gwave * 2;
    if (row >= nrows) return;

    // Prologue: issue first iteration's loads.
    const f32x4* r0 = reinterpret_cast<const f32x4*>(in + (size_t)row * 512);
    const f32x4* r1 = reinterpret_cast<const f32x4*>(in + (size_t)(row + 1) * 512);
    f32x4 a0 = __builtin_nontemporal_load(r0 + lane);
    f32x4 b0 = __builtin_nontemporal_load(r0 + lane + 64);
    f32x4 a1 = __builtin_nontemporal_load(r1 + lane);
    f32x4 b1 = __builtin_nontemporal_load(r1 + lane + 64);

    while (true) {
        // Issue NEXT iteration's loads before touching current data.
        const int nrow = row + stride;
        f32x4 na0 = {}, nb0 = {}, na1 = {}, nb1 = {};
        if (nrow < nrows) {
            const f32x4* p0 = reinterpret_cast<const f32x4*>(in + (size_t)nrow * 512);
            const f32x4* p1 = reinterpret_cast<const f32x4*>(in + (size_t)(nrow + 1) * 512);
            na0 = __builtin_nontemporal_load(p0 + lane);
            nb0 = __builtin_nontemporal_load(p0 + lane + 64);
            na1 = __builtin_nontemporal_load(p1 + lane);
            nb1 = __builtin_nontemporal_load(p1 + lane + 64);
        }

        // Reduce current rows.
        float m0 = fmaxf(fmaxf(fmaxf(a0.x, a0.y), fmaxf(a0.z, a0.w)),
                         fmaxf(fmaxf(b0.x, b0.y), fmaxf(b0.z, b0.w)));
        float m1 = fmaxf(fmaxf(fmaxf(a1.x, a1.y), fmaxf(a1.z, a1.w)),
                         fmaxf(fmaxf(b1.x, b1.y), fmaxf(b1.z, b1.w)));
        #pragma unroll
        for (int off = 32; off > 0; off >>= 1) {
            m0 = fmaxf(m0, __shfl_xor(m0, off, 64));
            m1 = fmaxf(m1, __shfl_xor(m1, off, 64));
        }

        i32x4 oa0, ob0, oa1, ob1;
        oa0.x = (a0.x == m0); oa0.y = (a0.y == m0); oa0.z = (a0.z == m0); oa0.w = (a0.w == m0);
        ob0.x = (b0.x == m0); ob0.y = (b0.y == m0); ob0.z = (b0.z == m0); ob0.w = (b0.w == m0);
        oa1.x = (a1.x == m1); oa1.y = (a1.y == m1); oa1.z = (a1.z == m1); oa1.w = (a1.w == m1);
        ob1.x = (b1.x == m1); ob1.y = (b1.y == m1); ob1.z = (b1.z == m1); ob1.w = (b1.w == m1);

        i32x4* w0 = reinterpret_cast<i32x4*>(out + (size_t)row * 512);
        i32x4* w1 = reinterpret_cast<i32x4*>(out + (size_t)(row + 1) * 512);
        __builtin_nontemporal_store(oa0, w0 + lane);
        __builtin_nontemporal_store(ob0, w0 + lane + 64);
        __builtin_nontemporal_store(oa1, w1 + lane);
        __builtin_nontemporal_store(ob1, w1 + lane + 64);

        if (nrow >= nrows) break;
        row = nrow;
        a0 = na0; b0 = nb0; a1 = na1; b1 = nb1;
    }
}

extern "C" void kernel_launch(void* const* d_in, const int* in_sizes, int n_in,
                              void* d_out, int out_size, void* d_ws, size_t ws_size,
                              hipStream_t stream) {
    const float* in = (const float*)d_in[0];
    int* out = (int*)d_out;
    const int D = 512;
    const int nrows = in_sizes[0] / D;   // 200704
    int grid = 2048;                     // ~8 blocks/CU, persistent
    const int max_needed = (nrows + 7) / 8;  // 4 waves/block * 2 rows/wave
    if (grid > max_needed) grid = max_needed;
    rowmax_mask_kernel<<<grid, 256, 0, stream>>>(in, out, nrows);
}